// Round 9
// baseline (453.271 us; speedup 1.0000x reference)
//
#include <hip/hip_runtime.h>

#define N_NODES 10000
#define E_EDGES 150000
#define KNB     15
#define EBLOCKS 587   // ceil(E/256)

// ---------------------------------------------------------------------------
// CSR count: parallel global atomics — NEVER single-block this (R7 lesson).
// ---------------------------------------------------------------------------
__global__ void count_kernel(const int* __restrict__ idxs, int* __restrict__ cnt, int e) {
    int i = blockIdx.x * blockDim.x + threadIdx.x;
    if (i < e) atomicAdd(&cnt[idxs[i]], 1);
}

// ---------------------------------------------------------------------------
// gemm_tile2 (MR=2) — weight-space folds only
// ---------------------------------------------------------------------------
__device__ __forceinline__
void gemm_tile2(const float* __restrict__ A, int K,
                const float* __restrict__ Blo, const float* __restrict__ Bhi, int ldB,
                float* __restrict__ C, int ldC, int M,
                int rowBlk, int colBlk) {
    __shared__ float As2[16][34];
    __shared__ float Bs2[16][64];
    int tid = threadIdx.x;
    int tn  = tid & 15, tm = tid >> 4;
    int arow = tid >> 3, acB = (tid & 7) << 1;
    int brow = tid >> 4, bcol = (tid & 15) << 2;
    int rowBase = rowBlk * 32, colBase = colBlk * 64;

    bool half = (Bhi != nullptr) && (colBase >= 128);
    const float* B = half ? Bhi : Blo;
    int bj = colBase - (half ? 128 : 0) + bcol;

    float2 av; float4 bv;
    auto loadA = [&](int k0, float2& dst) {
        int gr = rowBase + arow;
        if (gr < M) dst = *(const float2*)(A + (size_t)gr * K + k0 + acB);
        else { dst.x = dst.y = 0.f; }
    };
    auto loadB = [&](int k0, float4& dst) {
        dst = *(const float4*)(B + (size_t)(k0 + brow) * ldB + bj);
    };
    loadA(0, av); loadB(0, bv);

    float acc[2][4] = {};
    for (int k0 = 0; k0 < K; k0 += 16) {
        __syncthreads();
        As2[acB + 0][arow] = av.x; As2[acB + 1][arow] = av.y;
        *(float4*)&Bs2[brow][bcol] = bv;
        __syncthreads();
        if (k0 + 16 < K) { loadA(k0 + 16, av); loadB(k0 + 16, bv); }
#pragma unroll
        for (int k = 0; k < 16; ++k) {
            float4 b = *(const float4*)&Bs2[k][tn << 2];
            float2 a = *(const float2*)&As2[k][tm << 1];
            acc[0][0] = fmaf(a.x, b.x, acc[0][0]); acc[0][1] = fmaf(a.x, b.y, acc[0][1]);
            acc[0][2] = fmaf(a.x, b.z, acc[0][2]); acc[0][3] = fmaf(a.x, b.w, acc[0][3]);
            acc[1][0] = fmaf(a.y, b.x, acc[1][0]); acc[1][1] = fmaf(a.y, b.y, acc[1][1]);
            acc[1][2] = fmaf(a.y, b.z, acc[1][2]); acc[1][3] = fmaf(a.y, b.w, acc[1][3]);
        }
    }
#pragma unroll
    for (int i = 0; i < 2; ++i) {
        int row = rowBase + tm * 2 + i;
        if (row >= M) continue;
#pragma unroll
        for (int j = 0; j < 4; ++j)
            C[(size_t)row * ldC + colBase + (tn << 2) + j] = acc[i][j];
    }
}

// ---------------------------------------------------------------------------
// scanfold: block 0 = prefix-scan of cnt (writes eoff/maskv, zeroes fillc);
// blocks 1..40 = weight folds (M1, M2, WH, v1, v2, bu2, bx2).
// ---------------------------------------------------------------------------
__global__ __launch_bounds__(256)
void scanfold_kernel(const float* __restrict__ mw2, const float* __restrict__ mb2,
                     const float* __restrict__ nw1, const float* __restrict__ nb2,
                     const float* __restrict__ nw2,
                     const float* __restrict__ m2w1, const float* __restrict__ m2b1,
                     const float* __restrict__ m2w2, const float* __restrict__ m2b2,
                     const float* __restrict__ n2w1, const float* __restrict__ n2b1,
                     float* __restrict__ M1, float* __restrict__ M2,
                     float* __restrict__ WH,
                     float* __restrict__ v1, float* __restrict__ v2,
                     float* __restrict__ bu2, float* __restrict__ bx2,
                     const int* __restrict__ cnt, int* __restrict__ eoff,
                     float* __restrict__ maskv, int* __restrict__ fillc) {
    int b = blockIdx.x;
    if (b == 0) {
        __shared__ int ssum[256];
        int tid = threadIdx.x;
        const int CH = 40;
        int base = tid * CH;
        int v[CH]; int s = 0;
#pragma unroll
        for (int q = 0; q < CH; ++q) {
            int i = base + q;
            v[q] = (i < N_NODES) ? cnt[i] : 0;
            s += v[q];
        }
        ssum[tid] = s;
        __syncthreads();
        for (int off = 1; off < 256; off <<= 1) {
            int t = (tid >= off) ? ssum[tid - off] : 0;
            __syncthreads();
            ssum[tid] += t;
            __syncthreads();
        }
        int ex = ssum[tid] - s;
#pragma unroll
        for (int q = 0; q < CH; ++q) {
            int i = base + q;
            if (i < N_NODES) {
                eoff[i]  = ex;
                maskv[i] = (v[q] > 0) ? 1.f : 0.f;
                fillc[i] = 0;
                ex += v[q];
            }
        }
        return;
    }
    b -= 1;
    if (b < 8) {
        gemm_tile2(mw2, 784, nw1 + 784 * 128, nullptr, 128, M1, 128, 128, b >> 1, b & 1);
    } else if (b < 16) {
        int t = b - 8;
        gemm_tile2(m2w2, 128, n2w1 + 128 * 128, nullptr, 128, M2, 128, 128, t >> 1, t & 1);
    } else if (b < 32) {
        int t = b - 16;
        gemm_tile2(nw2, 128, m2w1, n2w1, 128, WH, 256, 128, t >> 2, t & 3);
    } else {
        __shared__ float red[256];
        int t  = (b - 32) >> 1;
        int j  = ((b - 32) & 1) * 64 + (threadIdx.x & 63);
        int kq = threadIdx.x >> 6;
        const float* bvec; const float* Bv; const float* add; float* out; int Kv;
        if (t == 0)      { bvec = mb2;  Bv = nw1 + 784 * 128;  add = nullptr; out = v1;  Kv = 784; }
        else if (t == 1) { bvec = m2b2; Bv = n2w1 + 128 * 128; add = nullptr; out = v2;  Kv = 128; }
        else if (t == 2) { bvec = nb2;  Bv = m2w1;             add = m2b1;    out = bu2; Kv = 128; }
        else             { bvec = nb2;  Bv = n2w1;             add = n2b1;    out = bx2; Kv = 128; }
        float acc = 0.f;
        for (int k = kq; k < Kv; k += 4) acc = fmaf(bvec[k], Bv[k * 128 + j], acc);
        red[threadIdx.x] = acc;
        __syncthreads();
        if (threadIdx.x < 64) {
            float tot = red[threadIdx.x] + red[threadIdx.x + 64] +
                        red[threadIdx.x + 128] + red[threadIdx.x + 192];
            out[j] = tot + (add ? add[j] : 0.f);
        }
    }
}

// ---------------------------------------------------------------------------
// CSR fill (standalone — must fully precede meganode's edge reads)
// ---------------------------------------------------------------------------
__global__ void fill_kernel(const int* __restrict__ idxs, const float* __restrict__ ea,
                            const int* __restrict__ eoff, int* __restrict__ fillc,
                            float* __restrict__ eas, int e) {
    int i = blockIdx.x * blockDim.x + threadIdx.x;
    if (i < e) {
        int s = idxs[i];
        int p = atomicAdd(&fillc[s], 1);
        eas[eoff[s] + p] = ea[i];
    }
}

// ---------------------------------------------------------------------------
// meganode: ALL node-local work in one kernel. 625 blocks x 16 rows each.
// Row-local chain (aggregation is by src => no cross-row gather until dist):
//   phaseA: UX1 = [x@mw1+mb1 | x@nw1+nb1+maskv*v1]   (K=784 GEMM, 2x8 micro)
//   msg1:   mhT = mean_e relu(u1 + ea*w1last)
//   phase1: ts  = relu(xn1 + mhT@M1)
//   phase2: UX2 = [ts@WHu+bu2 | ts@WHx+bx2+maskv*v2]
//   msg2:   mhT = mean_e relu(u2 + ea*w2last)
//   phase4: z2  = relu(xn2 + mhT@M2); proj = z2@pw + pb  (shuffle reduce)
// LDS ~40KB -> 3 blocks/CU.
// ---------------------------------------------------------------------------
__global__ __launch_bounds__(256)
void meganode_kernel(const float* __restrict__ x,
                     const float* __restrict__ mw1, const float* __restrict__ nw1,
                     const float* __restrict__ mb1, const float* __restrict__ nb1,
                     const float* __restrict__ v1, const float* __restrict__ maskv,
                     const float* __restrict__ w1last,
                     const float* __restrict__ eas, const int* __restrict__ eoff,
                     const int* __restrict__ cnt,
                     const float* __restrict__ M1, const float* __restrict__ WH,
                     const float* __restrict__ bu2, const float* __restrict__ bx2,
                     const float* __restrict__ v2,
                     const float* __restrict__ w2last,
                     const float* __restrict__ M2,
                     const float* __restrict__ pw, const float* __restrict__ pb,
                     float* __restrict__ UX1, float* __restrict__ UX2,
                     float* __restrict__ proj) {
    __shared__ float As[16][20];     // phaseA A-staging [k][row]
    __shared__ float Bs[16][264];    // B staging, reused by all GEMM phases
    __shared__ float mhT[128][18];   // msg means [k][m], stride 18 (even, low-conflict)
    __shared__ float ts[16][132];    // z1 rows
    __shared__ float ebuf[1024];     // CSR edge window
    int rowBase = blockIdx.x * 16;   // 625*16 = 10000 exact, no guards
    int tid = threadIdx.x;
    int tm2 = tid >> 5;              // 0..7 -> rows 2*tm2, 2*tm2+1
    int tn  = tid & 31;

    // ===== phaseA: K=784 GEMM, 16 rows x 256 cols =====
    {
        int bkr = tid >> 4, bc4 = (tid & 15) << 2;
        float4 aA; float4 bB[4];
        auto gload = [&](int k0) {
            if (tid < 64) {
                int row = tid >> 2, kq = (tid & 3) << 2;
                aA = *(const float4*)(x + (size_t)(rowBase + row) * 784 + k0 + kq);
            }
#pragma unroll
            for (int p = 0; p < 4; ++p) {
                int col = bc4 + p * 64;
                const float* Bp = (col < 128)
                    ? (mw1 + (size_t)(k0 + bkr) * 128 + col)
                    : (nw1 + (size_t)(k0 + bkr) * 128 + (col - 128));
                bB[p] = *(const float4*)Bp;
            }
        };
        auto sstore = [&]() {
            if (tid < 64) {
                int row = tid >> 2, kq = (tid & 3) << 2;
                As[kq + 0][row] = aA.x; As[kq + 1][row] = aA.y;
                As[kq + 2][row] = aA.z; As[kq + 3][row] = aA.w;
            }
#pragma unroll
            for (int p = 0; p < 4; ++p)
                *(float4*)&Bs[bkr][bc4 + p * 64] = bB[p];
        };
        gload(0);
        float acc[2][8] = {};
        for (int k0 = 0; k0 < 784; k0 += 16) {
            __syncthreads();
            sstore();
            __syncthreads();
            if (k0 + 16 < 784) gload(k0 + 16);
#pragma unroll
            for (int k = 0; k < 16; ++k) {
                float2 a  = *(const float2*)&As[k][tm2 << 1];
                float4 b0 = *(const float4*)&Bs[k][tn << 3];
                float4 b1 = *(const float4*)&Bs[k][(tn << 3) + 4];
                float br[8] = {b0.x, b0.y, b0.z, b0.w, b1.x, b1.y, b1.z, b1.w};
#pragma unroll
                for (int j = 0; j < 8; ++j) {
                    acc[0][j] = fmaf(a.x, br[j], acc[0][j]);
                    acc[1][j] = fmaf(a.y, br[j], acc[1][j]);
                }
            }
        }
        bool hi = tn >= 16;
        const float* bias = hi ? nb1 : mb1;
#pragma unroll
        for (int i = 0; i < 2; ++i) {
            int row = rowBase + (tm2 << 1) + i;
            float rm = hi ? maskv[row] : 0.f;
            float4 o0, o1; float* po0 = (float*)&o0; float* po1 = (float*)&o1;
#pragma unroll
            for (int j = 0; j < 4; ++j) {
                int cj0 = ((tn << 3) + j) & 127, cj1 = ((tn << 3) + 4 + j) & 127;
                float q0 = acc[i][j]     + bias[cj0];
                float q1 = acc[i][4 + j] + bias[cj1];
                if (hi) { q0 = fmaf(rm, v1[cj0], q0); q1 = fmaf(rm, v1[cj1], q1); }
                po0[j] = q0; po1[j] = q1;
            }
            float* orow = UX1 + (size_t)row * 256 + (tn << 3);
            *(float4*)orow       = o0;
            *(float4*)(orow + 4) = o1;
        }
    }
    __syncthreads();   // UX1 block-visible (global+shared fence semantics)

    // msg-mean phase (used twice)
    auto msg_phase = [&](const float* __restrict__ U, const float* __restrict__ wl) {
        int d = tid & 127, sub = tid >> 7;
        float w = wl[d];
        float uu[8], sum[8];
        int es[8], ec[8];
#pragma unroll
        for (int it = 0; it < 8; ++it) {
            int n  = rowBase + it * 2 + sub;
            ec[it] = cnt[n];
            es[it] = eoff[n];
            uu[it] = U[(size_t)n * 256 + d];
            sum[it] = 0.f;
        }
        int ebase = eoff[rowBase];
        int eend  = (rowBase + 16 < N_NODES) ? eoff[rowBase + 16] : E_EDGES;
        for (int w0 = ebase; w0 < eend; w0 += 1024) {
            int wlen = min(1024, eend - w0);
            __syncthreads();
            for (int q = tid; q < wlen; q += 256) ebuf[q] = eas[w0 + q];
            __syncthreads();
#pragma unroll
            for (int it = 0; it < 8; ++it) {
                int lo = max(es[it], w0), hiE = min(es[it] + ec[it], w0 + wlen);
                for (int e = lo; e < hiE; ++e)
                    sum[it] += fmaxf(fmaf(ebuf[e - w0], w, uu[it]), 0.f);
            }
        }
#pragma unroll
        for (int it = 0; it < 8; ++it)
            mhT[d][it * 2 + sub] = (ec[it] > 0) ? sum[it] / (float)ec[it] : 0.f;
    };

    // ===== msg1 =====
    msg_phase(UX1, w1last);
    __syncthreads();

    // ===== phase1: ts = relu(xn1 + mhT @ M1), 16x128 =====
    {
        float acc[2][4] = {};
        for (int k0 = 0; k0 < 128; k0 += 16) {
            int kr = tid >> 4, c8 = (tid & 15) << 3;
            *(float4*)&Bs[kr][c8]     = *(const float4*)(M1 + (size_t)(k0 + kr) * 128 + c8);
            *(float4*)&Bs[kr][c8 + 4] = *(const float4*)(M1 + (size_t)(k0 + kr) * 128 + c8 + 4);
            __syncthreads();
#pragma unroll
            for (int k = 0; k < 16; ++k) {
                float2 a = *(const float2*)&mhT[k0 + k][tm2 << 1];
                float4 b = *(const float4*)&Bs[k][tn << 2];
                acc[0][0] = fmaf(a.x, b.x, acc[0][0]); acc[0][1] = fmaf(a.x, b.y, acc[0][1]);
                acc[0][2] = fmaf(a.x, b.z, acc[0][2]); acc[0][3] = fmaf(a.x, b.w, acc[0][3]);
                acc[1][0] = fmaf(a.y, b.x, acc[1][0]); acc[1][1] = fmaf(a.y, b.y, acc[1][1]);
                acc[1][2] = fmaf(a.y, b.z, acc[1][2]); acc[1][3] = fmaf(a.y, b.w, acc[1][3]);
            }
            __syncthreads();
        }
#pragma unroll
        for (int i = 0; i < 2; ++i) {
            int row = rowBase + (tm2 << 1) + i;
            float4 xn = *(const float4*)(UX1 + (size_t)row * 256 + 128 + (tn << 2));
            float4 o;
            o.x = fmaxf(acc[i][0] + xn.x, 0.f);
            o.y = fmaxf(acc[i][1] + xn.y, 0.f);
            o.z = fmaxf(acc[i][2] + xn.z, 0.f);
            o.w = fmaxf(acc[i][3] + xn.w, 0.f);
            *(float4*)&ts[(tm2 << 1) + i][tn << 2] = o;
        }
    }

    // ===== phase2: UX2 = ts @ WH + bias (+maskv*v2 on hi), 16x256 =====
    {
        float acc[2][8] = {};
        for (int k0 = 0; k0 < 128; k0 += 16) {
            int kr = tid >> 4, c4 = (tid & 15) << 2;
#pragma unroll
            for (int p = 0; p < 4; ++p)
                *(float4*)&Bs[kr][c4 + p * 64] =
                    *(const float4*)(WH + (size_t)(k0 + kr) * 256 + c4 + p * 64);
            __syncthreads();   // also orders ts writes before reads
#pragma unroll
            for (int k = 0; k < 16; ++k) {
                float4 b0 = *(const float4*)&Bs[k][tn << 3];
                float4 b1 = *(const float4*)&Bs[k][(tn << 3) + 4];
                float br[8] = {b0.x, b0.y, b0.z, b0.w, b1.x, b1.y, b1.z, b1.w};
#pragma unroll
                for (int i = 0; i < 2; ++i) {
                    float a = ts[(tm2 << 1) + i][k0 + k];
#pragma unroll
                    for (int j = 0; j < 8; ++j)
                        acc[i][j] = fmaf(a, br[j], acc[i][j]);
                }
            }
            __syncthreads();
        }
        bool hi = tn >= 16;
        const float* bias = hi ? bx2 : bu2;
#pragma unroll
        for (int i = 0; i < 2; ++i) {
            int row = rowBase + (tm2 << 1) + i;
            float rm = maskv[row];
            float4 o0, o1; float* po0 = (float*)&o0; float* po1 = (float*)&o1;
#pragma unroll
            for (int j = 0; j < 4; ++j) {
                int cj0 = ((tn << 3) + j) & 127, cj1 = ((tn << 3) + 4 + j) & 127;
                float q0 = acc[i][j]     + bias[cj0];
                float q1 = acc[i][4 + j] + bias[cj1];
                if (hi) { q0 = fmaf(rm, v2[cj0], q0); q1 = fmaf(rm, v2[cj1], q1); }
                po0[j] = q0; po1[j] = q1;
            }
            float* orow = UX2 + (size_t)row * 256 + (tn << 3);
            *(float4*)orow       = o0;
            *(float4*)(orow + 4) = o1;
        }
    }
    __syncthreads();   // UX2 block-visible

    // ===== msg2 =====
    msg_phase(UX2, w2last);

    // ===== phase4: z2 = relu(xn2 + mhT@M2); proj = z2@pw + pb =====
    {
        float acc[2][4] = {};
        for (int k0 = 0; k0 < 128; k0 += 16) {
            int kr = tid >> 4, c8 = (tid & 15) << 3;
            *(float4*)&Bs[kr][c8]     = *(const float4*)(M2 + (size_t)(k0 + kr) * 128 + c8);
            *(float4*)&Bs[kr][c8 + 4] = *(const float4*)(M2 + (size_t)(k0 + kr) * 128 + c8 + 4);
            __syncthreads();   // also orders msg2's mhT writes
#pragma unroll
            for (int k = 0; k < 16; ++k) {
                float2 a = *(const float2*)&mhT[k0 + k][tm2 << 1];
                float4 b = *(const float4*)&Bs[k][tn << 2];
                acc[0][0] = fmaf(a.x, b.x, acc[0][0]); acc[0][1] = fmaf(a.x, b.y, acc[0][1]);
                acc[0][2] = fmaf(a.x, b.z, acc[0][2]); acc[0][3] = fmaf(a.x, b.w, acc[0][3]);
                acc[1][0] = fmaf(a.y, b.x, acc[1][0]); acc[1][1] = fmaf(a.y, b.y, acc[1][1]);
                acc[1][2] = fmaf(a.y, b.z, acc[1][2]); acc[1][3] = fmaf(a.y, b.w, acc[1][3]);
            }
            __syncthreads();
        }
        float pp0[2], pp1[2];
#pragma unroll
        for (int i = 0; i < 2; ++i) {
            int row = rowBase + (tm2 << 1) + i;
            float4 xn = *(const float4*)(UX2 + (size_t)row * 256 + 128 + (tn << 2));
            float t0 = fmaxf(acc[i][0] + xn.x, 0.f);
            float t1 = fmaxf(acc[i][1] + xn.y, 0.f);
            float t2 = fmaxf(acc[i][2] + xn.z, 0.f);
            float t3 = fmaxf(acc[i][3] + xn.w, 0.f);
            int c = tn << 2;
            pp0[i] = fmaf(t3, pw[2*(c+3)],   fmaf(t2, pw[2*(c+2)],   fmaf(t1, pw[2*(c+1)],   t0 * pw[2*c])));
            pp1[i] = fmaf(t3, pw[2*(c+3)+1], fmaf(t2, pw[2*(c+2)+1], fmaf(t1, pw[2*(c+1)+1], t0 * pw[2*c+1])));
        }
        for (int off = 16; off > 0; off >>= 1) {
            pp0[0] += __shfl_xor(pp0[0], off, 64);
            pp0[1] += __shfl_xor(pp0[1], off, 64);
            pp1[0] += __shfl_xor(pp1[0], off, 64);
            pp1[1] += __shfl_xor(pp1[1], off, 64);
        }
        if (tn == 0) {
#pragma unroll
            for (int i = 0; i < 2; ++i) {
                int row = rowBase + (tm2 << 1) + i;
                proj[2 * row]     = pp0[i] + pb[0];
                proj[2 * row + 1] = pp1[i] + pb[1];
            }
        }
    }
}

__global__ void dist_kernel(const float* __restrict__ proj, const int* __restrict__ idxs,
                            float* __restrict__ out, int e) {
    int i = blockIdx.x * blockDim.x + threadIdx.x;
    if (i >= e) return;
    int n = i / KNB;
    int m = idxs[i];
    float2 pn = *(const float2*)(proj + 2 * n);
    float2 pm = *(const float2*)(proj + 2 * m);
    float dx = pn.x - pm.x;
    float dy = pn.y - pm.y;
    out[i] = dx * dx + dy * dy;
}

// ---------------------------------------------------------------------------
extern "C" void kernel_launch(void* const* d_in, const int* in_sizes, int n_in,
                              void* d_out, int out_size, void* d_ws, size_t ws_size,
                              hipStream_t stream) {
    (void)in_sizes; (void)n_in; (void)out_size; (void)ws_size;
    const float* x    = (const float*)d_in[0];
    const float* eatt = (const float*)d_in[1];
    const int*   idxs = (const int*)d_in[2];
    const float* mw1  = (const float*)d_in[3];
    const float* mb1  = (const float*)d_in[4];
    const float* mw2  = (const float*)d_in[5];
    const float* mb2  = (const float*)d_in[6];
    const float* nw1  = (const float*)d_in[7];
    const float* nb1  = (const float*)d_in[8];
    const float* nw2  = (const float*)d_in[9];
    const float* nb2  = (const float*)d_in[10];
    const float* m2w1 = (const float*)d_in[11];
    const float* m2b1 = (const float*)d_in[12];
    const float* m2w2 = (const float*)d_in[13];
    const float* m2b2 = (const float*)d_in[14];
    const float* n2w1 = (const float*)d_in[15];
    const float* n2b1 = (const float*)d_in[16];
    const float* n2w2 = (const float*)d_in[17];
    const float* n2b2 = (const float*)d_in[18];
    float* out = (float*)d_out;

    float* fws   = (float*)d_ws;
    float* UX1   = fws;                   // 10000*256
    float* UX2   = fws + 2560000;         // 10000*256
    float* proj  = fws + 5120000;         // 10000*2
    float* maskv = fws + 5140000;         // 10000
    float* eas   = fws + 5150016;         // 150000
    float* M1    = fws + 5300016;         // 128*128
    float* M2    = fws + 5316400;         // 128*128
    float* WH    = fws + 5332784;         // 128*256
    float* v1    = fws + 5365552;         // 128
    float* v2    = fws + 5365680;         // 128
    float* bu2   = fws + 5365808;         // 128
    float* bx2   = fws + 5365936;         // 128
    int*   cnt   = (int*)(fws + 5366064);
    int*   fillc = cnt + N_NODES;
    int*   eoff  = fillc + N_NODES;

    // L1-2: zero cnt, parallel histogram
    hipMemsetAsync(cnt, 0, N_NODES * sizeof(int), stream);
    count_kernel<<<EBLOCKS, 256, 0, stream>>>(idxs, cnt, E_EDGES);

    // L3: prefix-scan (block 0, zeroes fillc) + all weight folds
    scanfold_kernel<<<41, 256, 0, stream>>>(mw2, mb2, nw1, nb2, nw2,
                                            m2w1, m2b1, m2w2, m2b2, n2w1, n2b1,
                                            M1, M2, WH, v1, v2, bu2, bx2,
                                            cnt, eoff, maskv, fillc);

    // L4: CSR fill
    fill_kernel<<<EBLOCKS, 256, 0, stream>>>(idxs, eatt, eoff, fillc, eas, E_EDGES);

    // L5: the entire row-local node pipeline in one kernel
    meganode_kernel<<<625, 256, 0, stream>>>(x, mw1, nw1, mb1, nb1, v1, maskv,
                                             mw1 + 784 * 128,
                                             eas, eoff, cnt,
                                             M1, WH, bu2, bx2, v2,
                                             m2w1 + 128 * 128,
                                             M2, n2w2, n2b2,
                                             UX1, UX2, proj);

    // L6: per-edge squared distances (needs all proj -> separate dispatch)
    dist_kernel<<<EBLOCKS, 256, 0, stream>>>(proj, idxs, out, E_EDGES);
}

// Round 10
// 359.026 us; speedup vs baseline: 1.2625x; 1.2625x over previous
//
#include <hip/hip_runtime.h>

#define N_NODES 10000
#define E_EDGES 150000
#define KNB     15
#define EBLOCKS 587   // ceil(E/256)
#define GEMM_BLOCKS 628   // 157 rowBlks x 4 colBlks

// ---------------------------------------------------------------------------
// CSR count: parallel global atomics — NEVER single-block this (R7 lesson).
// ---------------------------------------------------------------------------
__global__ void count_kernel(const int* __restrict__ idxs, int* __restrict__ cnt, int e) {
    int i = blockIdx.x * blockDim.x + threadIdx.x;
    if (i < e) atomicAdd(&cnt[idxs[i]], 1);
}

// ---------------------------------------------------------------------------
// gemm_tile2 (MR=2) — weight-space folds only
// ---------------------------------------------------------------------------
__device__ __forceinline__
void gemm_tile2(const float* __restrict__ A, int K,
                const float* __restrict__ Blo, const float* __restrict__ Bhi, int ldB,
                float* __restrict__ C, int ldC, int M,
                int rowBlk, int colBlk) {
    __shared__ float As2[16][34];
    __shared__ float Bs2[16][64];
    int tid = threadIdx.x;
    int tn  = tid & 15, tm = tid >> 4;
    int arow = tid >> 3, acB = (tid & 7) << 1;
    int brow = tid >> 4, bcol = (tid & 15) << 2;
    int rowBase = rowBlk * 32, colBase = colBlk * 64;

    bool half = (Bhi != nullptr) && (colBase >= 128);
    const float* B = half ? Bhi : Blo;
    int bj = colBase - (half ? 128 : 0) + bcol;

    float2 av; float4 bv;
    auto loadA = [&](int k0, float2& dst) {
        int gr = rowBase + arow;
        if (gr < M) dst = *(const float2*)(A + (size_t)gr * K + k0 + acB);
        else { dst.x = dst.y = 0.f; }
    };
    auto loadB = [&](int k0, float4& dst) {
        dst = *(const float4*)(B + (size_t)(k0 + brow) * ldB + bj);
    };
    loadA(0, av); loadB(0, bv);

    float acc[2][4] = {};
    for (int k0 = 0; k0 < K; k0 += 16) {
        __syncthreads();
        As2[acB + 0][arow] = av.x; As2[acB + 1][arow] = av.y;
        *(float4*)&Bs2[brow][bcol] = bv;
        __syncthreads();
        if (k0 + 16 < K) { loadA(k0 + 16, av); loadB(k0 + 16, bv); }
#pragma unroll
        for (int k = 0; k < 16; ++k) {
            float4 b = *(const float4*)&Bs2[k][tn << 2];
            float2 a = *(const float2*)&As2[k][tm << 1];
            acc[0][0] = fmaf(a.x, b.x, acc[0][0]); acc[0][1] = fmaf(a.x, b.y, acc[0][1]);
            acc[0][2] = fmaf(a.x, b.z, acc[0][2]); acc[0][3] = fmaf(a.x, b.w, acc[0][3]);
            acc[1][0] = fmaf(a.y, b.x, acc[1][0]); acc[1][1] = fmaf(a.y, b.y, acc[1][1]);
            acc[1][2] = fmaf(a.y, b.z, acc[1][2]); acc[1][3] = fmaf(a.y, b.w, acc[1][3]);
        }
    }
#pragma unroll
    for (int i = 0; i < 2; ++i) {
        int row = rowBase + tm * 2 + i;
        if (row >= M) continue;
#pragma unroll
        for (int j = 0; j < 4; ++j)
            C[(size_t)row * ldC + colBase + (tn << 2) + j] = acc[i][j];
    }
}

// ---------------------------------------------------------------------------
// scanfold: block 0 = prefix-scan of cnt (writes eoff/maskv, zeroes fillc);
// blocks 1..40 = weight folds (M1, M2, WH, v1, v2, bu2, bx2).
// ---------------------------------------------------------------------------
__global__ __launch_bounds__(256)
void scanfold_kernel(const float* __restrict__ mw2, const float* __restrict__ mb2,
                     const float* __restrict__ nw1, const float* __restrict__ nb2,
                     const float* __restrict__ nw2,
                     const float* __restrict__ m2w1, const float* __restrict__ m2b1,
                     const float* __restrict__ m2w2, const float* __restrict__ m2b2,
                     const float* __restrict__ n2w1, const float* __restrict__ n2b1,
                     float* __restrict__ M1, float* __restrict__ M2,
                     float* __restrict__ WH,
                     float* __restrict__ v1, float* __restrict__ v2,
                     float* __restrict__ bu2, float* __restrict__ bx2,
                     const int* __restrict__ cnt, int* __restrict__ eoff,
                     float* __restrict__ maskv, int* __restrict__ fillc) {
    int b = blockIdx.x;
    if (b == 0) {
        __shared__ int ssum[256];
        int tid = threadIdx.x;
        const int CH = 40;
        int base = tid * CH;
        int v[CH]; int s = 0;
#pragma unroll
        for (int q = 0; q < CH; ++q) {
            int i = base + q;
            v[q] = (i < N_NODES) ? cnt[i] : 0;
            s += v[q];
        }
        ssum[tid] = s;
        __syncthreads();
        for (int off = 1; off < 256; off <<= 1) {
            int t = (tid >= off) ? ssum[tid - off] : 0;
            __syncthreads();
            ssum[tid] += t;
            __syncthreads();
        }
        int ex = ssum[tid] - s;
#pragma unroll
        for (int q = 0; q < CH; ++q) {
            int i = base + q;
            if (i < N_NODES) {
                eoff[i]  = ex;
                maskv[i] = (v[q] > 0) ? 1.f : 0.f;
                fillc[i] = 0;
                ex += v[q];
            }
        }
        return;
    }
    b -= 1;
    if (b < 8) {
        gemm_tile2(mw2, 784, nw1 + 784 * 128, nullptr, 128, M1, 128, 128, b >> 1, b & 1);
    } else if (b < 16) {
        int t = b - 8;
        gemm_tile2(m2w2, 128, n2w1 + 128 * 128, nullptr, 128, M2, 128, 128, t >> 1, t & 1);
    } else if (b < 32) {
        int t = b - 16;
        gemm_tile2(nw2, 128, m2w1, n2w1, 128, WH, 256, 128, t >> 2, t & 3);
    } else {
        __shared__ float red[256];
        int t  = (b - 32) >> 1;
        int j  = ((b - 32) & 1) * 64 + (threadIdx.x & 63);
        int kq = threadIdx.x >> 6;
        const float* bvec; const float* Bv; const float* add; float* out; int Kv;
        if (t == 0)      { bvec = mb2;  Bv = nw1 + 784 * 128;  add = nullptr; out = v1;  Kv = 784; }
        else if (t == 1) { bvec = m2b2; Bv = n2w1 + 128 * 128; add = nullptr; out = v2;  Kv = 128; }
        else if (t == 2) { bvec = nb2;  Bv = m2w1;             add = m2b1;    out = bu2; Kv = 128; }
        else             { bvec = nb2;  Bv = n2w1;             add = n2b1;    out = bx2; Kv = 128; }
        float acc = 0.f;
        for (int k = kq; k < Kv; k += 4) acc = fmaf(bvec[k], Bv[k * 128 + j], acc);
        red[threadIdx.x] = acc;
        __syncthreads();
        if (threadIdx.x < 64) {
            float tot = red[threadIdx.x] + red[threadIdx.x + 64] +
                        red[threadIdx.x + 128] + red[threadIdx.x + 192];
            out[j] = tot + (add ? add[j] : 0.f);
        }
    }
}

// ---------------------------------------------------------------------------
// gemm784 tile — R3/R8-proven: 256 thr, 64x64 tile, 4x4 micro,
// LDS A(transposed, pad 68) + B, register prefetch, 2 barriers/k-tile.
// ---------------------------------------------------------------------------
__device__ __forceinline__
void gemm784_tile(const float* __restrict__ A,
                  const float* __restrict__ B0, const float* __restrict__ B1,
                  const float* __restrict__ biasLo, const float* __restrict__ biasHi,
                  const float* __restrict__ vhi, const float* __restrict__ rowmask,
                  float* __restrict__ C, int M, int gb) {
    __shared__ float As[16][68];
    __shared__ float Bs[16][64];
    int rb = gb >> 2, cb = gb & 3;
    int tid = threadIdx.x;
    int tm = tid >> 4, tn = tid & 15;
    int arow = tid >> 2, ac4 = (tid & 3) << 2;
    int brow = tid >> 4, bc4 = (tid & 15) << 2;
    int rowBase = rb * 64, colBase = cb * 64;
    bool hi = colBase >= 128;
    const float* B    = hi ? B1 : B0;
    const float* bias = hi ? biasHi : biasLo;
    int bj = ((cb & 1) << 6) + bc4;

    int gr = rowBase + arow; if (gr > M - 1) gr = M - 1;   // clamp; stores guarded
    const float* Ap = A + (size_t)gr * 784;

    float4 av, bv;
    av = *(const float4*)(Ap + ac4);
    bv = *(const float4*)(B + (size_t)brow * 128 + bj);

    float acc[4][4] = {};
    for (int k0 = 0; k0 < 784; k0 += 16) {
        __syncthreads();
        As[ac4 + 0][arow] = av.x;
        As[ac4 + 1][arow] = av.y;
        As[ac4 + 2][arow] = av.z;
        As[ac4 + 3][arow] = av.w;
        *(float4*)&Bs[brow][bc4] = bv;
        __syncthreads();
        if (k0 + 16 < 784) {
            av = *(const float4*)(Ap + k0 + 16 + ac4);
            bv = *(const float4*)(B + (size_t)(k0 + 16 + brow) * 128 + bj);
        }
#pragma unroll
        for (int k = 0; k < 16; ++k) {
            float4 a = *(const float4*)&As[k][tm << 2];
            float4 b = *(const float4*)&Bs[k][tn << 2];
            acc[0][0] = fmaf(a.x, b.x, acc[0][0]); acc[0][1] = fmaf(a.x, b.y, acc[0][1]);
            acc[0][2] = fmaf(a.x, b.z, acc[0][2]); acc[0][3] = fmaf(a.x, b.w, acc[0][3]);
            acc[1][0] = fmaf(a.y, b.x, acc[1][0]); acc[1][1] = fmaf(a.y, b.y, acc[1][1]);
            acc[1][2] = fmaf(a.y, b.z, acc[1][2]); acc[1][3] = fmaf(a.y, b.w, acc[1][3]);
            acc[2][0] = fmaf(a.z, b.x, acc[2][0]); acc[2][1] = fmaf(a.z, b.y, acc[2][1]);
            acc[2][2] = fmaf(a.z, b.z, acc[2][2]); acc[2][3] = fmaf(a.z, b.w, acc[2][3]);
            acc[3][0] = fmaf(a.w, b.x, acc[3][0]); acc[3][1] = fmaf(a.w, b.y, acc[3][1]);
            acc[3][2] = fmaf(a.w, b.z, acc[3][2]); acc[3][3] = fmaf(a.w, b.w, acc[3][3]);
        }
    }

#pragma unroll
    for (int i = 0; i < 4; ++i) {
        int row = rowBase + (tm << 2) + i;
        if (row >= M) continue;
        float rm = hi ? rowmask[row] : 0.f;
#pragma unroll
        for (int j = 0; j < 4; ++j) {
            int gcol = colBase + (tn << 2) + j;
            int cj   = gcol & 127;
            float v = acc[i][j] + bias[cj];
            if (hi) v = fmaf(rm, vhi[cj], v);
            C[(size_t)row * 256 + gcol] = v;
        }
    }
}

// ---------------------------------------------------------------------------
// fillgemm: blocks [0,587) CSR fill; blocks [587,1215) gemm784.
// ---------------------------------------------------------------------------
__global__ __launch_bounds__(256)
void fillgemm_kernel(const int* __restrict__ idxs, const float* __restrict__ ea,
                     const int* __restrict__ eoff, int* __restrict__ fillc,
                     float* __restrict__ eas,
                     const float* __restrict__ A,
                     const float* __restrict__ B0, const float* __restrict__ B1,
                     const float* __restrict__ biasLo, const float* __restrict__ biasHi,
                     const float* __restrict__ vhi, const float* __restrict__ rowmask,
                     float* __restrict__ C, int M) {
    int gb = blockIdx.x;
    if (gb < EBLOCKS) {
        int i = gb * 256 + threadIdx.x;
        if (i < E_EDGES) {
            int s = idxs[i];
            int p = atomicAdd(&fillc[s], 1);
            eas[eoff[s] + p] = ea[i];
        }
        return;
    }
    gemm784_tile(A, B0, B1, biasLo, biasHi, vhi, rowmask, C, M, gb - EBLOCKS);
}

// ---------------------------------------------------------------------------
// fused_tail (grid 313, 32 rows/block) = R8's fused_mid + fused_last in one:
//  msg1:   mhT = mean_e relu(u1 + ea*w1last); rmask
//  phase1: ts  = relu(xn1 + mhT@M1)
//  phase2: UX2 = [ts@WHu+bu2 | ts@WHx+bx2+rm*v2]  (global, own rows)
//  msg2:   mhT = mean_e relu(u2 + ea*w2last)
//  phase4: z2  = relu(xn2 + mhT@M2); proj = z2@pw + pb
// Block-local global round-trip (write -> __syncthreads -> own-row read)
// verified by R9's meganode correctness.
// ---------------------------------------------------------------------------
__global__ __launch_bounds__(256)
void fused_tail_kernel(const float* __restrict__ UX, const float* __restrict__ w1last,
                       const float* __restrict__ eas, const int* __restrict__ eoff,
                       const int* __restrict__ cnt,
                       const float* __restrict__ M1mat, const float* __restrict__ WH,
                       const float* __restrict__ bu2, const float* __restrict__ bx2,
                       const float* __restrict__ v2,
                       const float* __restrict__ w2last, const float* __restrict__ M2mat,
                       const float* __restrict__ pw, const float* __restrict__ pb,
                       float* __restrict__ UX2, float* __restrict__ proj, int M) {
    __shared__ float mhT[128][36];
    __shared__ float ts[32][132];
    __shared__ float Bs[16][264];
    __shared__ float ebuf[1536];
    __shared__ float rmask[32];
    int rowBase = blockIdx.x * 32;
    int tid = threadIdx.x;

    // ---- msg1 ----
    {
        int d = tid & 127, sub = tid >> 7;
        float w = w1last[d];
        float uu[16], sum[16];
        int es[16], ec[16];
#pragma unroll
        for (int it = 0; it < 16; ++it) {
            int n  = rowBase + it * 2 + sub;
            int nc = (n < M) ? n : M - 1;
            ec[it] = cnt[nc];
            es[it] = eoff[nc];
            uu[it] = UX[(size_t)nc * 256 + d];
            sum[it] = 0.f;
            if (d == 0) rmask[it * 2 + sub] = (ec[it] > 0) ? 1.f : 0.f;
        }
        int ebase = eoff[rowBase];
        int eend  = (rowBase + 32 < M) ? eoff[rowBase + 32] : E_EDGES;
        for (int w0 = ebase; w0 < eend; w0 += 1536) {
            int wlen = min(1536, eend - w0);
            __syncthreads();
            for (int q = tid; q < wlen; q += 256) ebuf[q] = eas[w0 + q];
            __syncthreads();
#pragma unroll
            for (int it = 0; it < 16; ++it) {
                int lo = max(es[it], w0), hi = min(es[it] + ec[it], w0 + wlen);
                for (int e = lo; e < hi; ++e)
                    sum[it] += fmaxf(fmaf(ebuf[e - w0], w, uu[it]), 0.f);
            }
        }
#pragma unroll
        for (int it = 0; it < 16; ++it)
            mhT[d][it * 2 + sub] = (ec[it] > 0) ? sum[it] / (float)ec[it] : 0.f;
    }
    __syncthreads();

    // ---- phase1: ts = relu(xn1 + mhT @ M1) ----
    {
        int tm = tid >> 5, tn = tid & 31;
        float acc[4][4] = {};
        for (int k0 = 0; k0 < 128; k0 += 16) {
#pragma unroll
            for (int t2 = 0; t2 < 2; ++t2) {
                int f2 = (tid << 1) | t2;
                int kr = f2 >> 5, c4 = (f2 & 31) << 2;
                *(float4*)&Bs[kr][c4] = *(const float4*)(M1mat + (size_t)(k0 + kr) * 128 + c4);
            }
            __syncthreads();
#pragma unroll
            for (int k = 0; k < 16; ++k) {
                float4 a = *(const float4*)&mhT[k0 + k][tm << 2];
                float4 b = *(const float4*)&Bs[k][tn << 2];
                acc[0][0] = fmaf(a.x, b.x, acc[0][0]); acc[0][1] = fmaf(a.x, b.y, acc[0][1]);
                acc[0][2] = fmaf(a.x, b.z, acc[0][2]); acc[0][3] = fmaf(a.x, b.w, acc[0][3]);
                acc[1][0] = fmaf(a.y, b.x, acc[1][0]); acc[1][1] = fmaf(a.y, b.y, acc[1][1]);
                acc[1][2] = fmaf(a.y, b.z, acc[1][2]); acc[1][3] = fmaf(a.y, b.w, acc[1][3]);
                acc[2][0] = fmaf(a.z, b.x, acc[2][0]); acc[2][1] = fmaf(a.z, b.y, acc[2][1]);
                acc[2][2] = fmaf(a.z, b.z, acc[2][2]); acc[2][3] = fmaf(a.z, b.w, acc[2][3]);
                acc[3][0] = fmaf(a.w, b.x, acc[3][0]); acc[3][1] = fmaf(a.w, b.y, acc[3][1]);
                acc[3][2] = fmaf(a.w, b.z, acc[3][2]); acc[3][3] = fmaf(a.w, b.w, acc[3][3]);
            }
            __syncthreads();
        }
#pragma unroll
        for (int i = 0; i < 4; ++i) {
            int row = rowBase + (tm << 2) + i;
            int rc  = (row < M) ? row : M - 1;
#pragma unroll
            for (int j = 0; j < 4; ++j) {
                int col = (tn << 2) + j;
                float v = acc[i][j] + UX[(size_t)rc * 256 + 128 + col];
                ts[(tm << 2) + i][col] = fmaxf(v, 0.f);
            }
        }
    }

    // ---- phase2: UX2 = ts @ WH + bias (+rm*v2) ----
    {
        int tm = tid >> 5, tn = tid & 31;
        float acc[4][8] = {};
        for (int k0 = 0; k0 < 128; k0 += 16) {
#pragma unroll
            for (int q = 0; q < 4; ++q) {
                int slot = (q << 8) + tid;
                int kr = slot >> 6, c4 = (slot & 63) << 2;
                *(float4*)&Bs[kr][c4] = *(const float4*)(WH + (size_t)(k0 + kr) * 256 + c4);
            }
            __syncthreads();   // also orders ts writes before reads
#pragma unroll
            for (int k = 0; k < 16; ++k) {
                float4 b0 = *(const float4*)&Bs[k][tn << 3];
                float4 b1 = *(const float4*)&Bs[k][(tn << 3) + 4];
                float br[8] = {b0.x, b0.y, b0.z, b0.w, b1.x, b1.y, b1.z, b1.w};
#pragma unroll
                for (int i = 0; i < 4; ++i) {
                    float a = ts[(tm << 2) + i][k0 + k];
#pragma unroll
                    for (int j = 0; j < 8; ++j)
                        acc[i][j] = fmaf(a, br[j], acc[i][j]);
                }
            }
            __syncthreads();
        }
        bool half = (tn >= 16);
        const float* bias = half ? bx2 : bu2;
#pragma unroll
        for (int i = 0; i < 4; ++i) {
            int row = rowBase + (tm << 2) + i;
            if (row >= M) continue;
            float rm = rmask[(tm << 2) + i];
            float4 o0, o1;
            float* po0 = (float*)&o0; float* po1 = (float*)&o1;
#pragma unroll
            for (int j = 0; j < 4; ++j) {
                int gcol0 = (tn << 3) + j, gcol1 = (tn << 3) + 4 + j;
                int cj0 = gcol0 & 127, cj1 = gcol1 & 127;
                float v0 = acc[i][j] + bias[cj0];
                float v1s = acc[i][4 + j] + bias[cj1];
                if (half) { v0 = fmaf(rm, v2[cj0], v0); v1s = fmaf(rm, v2[cj1], v1s); }
                po0[j] = v0; po1[j] = v1s;
            }
            float* orow = UX2 + (size_t)row * 256 + (tn << 3);
            *(float4*)(orow)     = o0;
            *(float4*)(orow + 4) = o1;
        }
    }
    __syncthreads();   // UX2 block-visible (own rows only are read below)

    // ---- msg2 ----
    {
        int d = tid & 127, sub = tid >> 7;
        float w = w2last[d];
        float uu[16], sum[16];
        int es[16], ec[16];
#pragma unroll
        for (int it = 0; it < 16; ++it) {
            int n  = rowBase + it * 2 + sub;
            int nc = (n < M) ? n : M - 1;
            ec[it] = cnt[nc];
            es[it] = eoff[nc];
            uu[it] = UX2[(size_t)nc * 256 + d];
            sum[it] = 0.f;
        }
        int ebase = eoff[rowBase];
        int eend  = (rowBase + 32 < M) ? eoff[rowBase + 32] : E_EDGES;
        for (int w0 = ebase; w0 < eend; w0 += 1536) {
            int wlen = min(1536, eend - w0);
            __syncthreads();
            for (int q = tid; q < wlen; q += 256) ebuf[q] = eas[w0 + q];
            __syncthreads();
#pragma unroll
            for (int it = 0; it < 16; ++it) {
                int lo = max(es[it], w0), hi = min(es[it] + ec[it], w0 + wlen);
                for (int e = lo; e < hi; ++e)
                    sum[it] += fmaxf(fmaf(ebuf[e - w0], w, uu[it]), 0.f);
            }
        }
#pragma unroll
        for (int it = 0; it < 16; ++it)
            mhT[d][it * 2 + sub] = (ec[it] > 0) ? sum[it] / (float)ec[it] : 0.f;
    }
    __syncthreads();

    // ---- phase4: z2 = relu(xn2 + mhT@M2); proj ----
    {
        int tm = tid >> 5, tn = tid & 31;
        float acc[4][4] = {};
        for (int k0 = 0; k0 < 128; k0 += 16) {
#pragma unroll
            for (int t2 = 0; t2 < 2; ++t2) {
                int f2 = (tid << 1) | t2;
                int kr = f2 >> 5, c4 = (f2 & 31) << 2;
                *(float4*)&Bs[kr][c4] = *(const float4*)(M2mat + (size_t)(k0 + kr) * 128 + c4);
            }
            __syncthreads();
#pragma unroll
            for (int k = 0; k < 16; ++k) {
                float4 a = *(const float4*)&mhT[k0 + k][tm << 2];
                float4 b = *(const float4*)&Bs[k][tn << 2];
                acc[0][0] = fmaf(a.x, b.x, acc[0][0]); acc[0][1] = fmaf(a.x, b.y, acc[0][1]);
                acc[0][2] = fmaf(a.x, b.z, acc[0][2]); acc[0][3] = fmaf(a.x, b.w, acc[0][3]);
                acc[1][0] = fmaf(a.y, b.x, acc[1][0]); acc[1][1] = fmaf(a.y, b.y, acc[1][1]);
                acc[1][2] = fmaf(a.y, b.z, acc[1][2]); acc[1][3] = fmaf(a.y, b.w, acc[1][3]);
                acc[2][0] = fmaf(a.z, b.x, acc[2][0]); acc[2][1] = fmaf(a.z, b.y, acc[2][1]);
                acc[2][2] = fmaf(a.z, b.z, acc[2][2]); acc[2][3] = fmaf(a.z, b.w, acc[2][3]);
                acc[3][0] = fmaf(a.w, b.x, acc[3][0]); acc[3][1] = fmaf(a.w, b.y, acc[3][1]);
                acc[3][2] = fmaf(a.w, b.z, acc[3][2]); acc[3][3] = fmaf(a.w, b.w, acc[3][3]);
            }
            __syncthreads();
        }
        float p0[4] = {}, p1[4] = {};
#pragma unroll
        for (int i = 0; i < 4; ++i) {
            int row = rowBase + (tm << 2) + i;
            int rc  = (row < M) ? row : M - 1;
#pragma unroll
            for (int j = 0; j < 4; ++j) {
                int col = (tn << 2) + j;
                float t = fmaxf(acc[i][j] + UX2[(size_t)rc * 256 + 128 + col], 0.f);
                p0[i] = fmaf(t, pw[col * 2],     p0[i]);
                p1[i] = fmaf(t, pw[col * 2 + 1], p1[i]);
            }
        }
#pragma unroll
        for (int i = 0; i < 4; ++i) {
            for (int off = 16; off > 0; off >>= 1) {
                p0[i] += __shfl_xor(p0[i], off, 64);
                p1[i] += __shfl_xor(p1[i], off, 64);
            }
        }
        if (tn == 0) {
#pragma unroll
            for (int i = 0; i < 4; ++i) {
                int row = rowBase + (tm << 2) + i;
                if (row < M) {
                    proj[row * 2]     = p0[i] + pb[0];
                    proj[row * 2 + 1] = p1[i] + pb[1];
                }
            }
        }
    }
}

__global__ void dist_kernel(const float* __restrict__ proj, const int* __restrict__ idxs,
                            float* __restrict__ out, int e) {
    int i = blockIdx.x * blockDim.x + threadIdx.x;
    if (i >= e) return;
    int n = i / KNB;
    int m = idxs[i];
    float2 pn = *(const float2*)(proj + 2 * n);
    float2 pm = *(const float2*)(proj + 2 * m);
    float dx = pn.x - pm.x;
    float dy = pn.y - pm.y;
    out[i] = dx * dx + dy * dy;
}

// ---------------------------------------------------------------------------
extern "C" void kernel_launch(void* const* d_in, const int* in_sizes, int n_in,
                              void* d_out, int out_size, void* d_ws, size_t ws_size,
                              hipStream_t stream) {
    (void)in_sizes; (void)n_in; (void)out_size; (void)ws_size;
    const float* x    = (const float*)d_in[0];
    const float* eatt = (const float*)d_in[1];
    const int*   idxs = (const int*)d_in[2];
    const float* mw1  = (const float*)d_in[3];
    const float* mb1  = (const float*)d_in[4];
    const float* mw2  = (const float*)d_in[5];
    const float* mb2  = (const float*)d_in[6];
    const float* nw1  = (const float*)d_in[7];
    const float* nb1  = (const float*)d_in[8];
    const float* nw2  = (const float*)d_in[9];
    const float* nb2  = (const float*)d_in[10];
    const float* m2w1 = (const float*)d_in[11];
    const float* m2b1 = (const float*)d_in[12];
    const float* m2w2 = (const float*)d_in[13];
    const float* m2b2 = (const float*)d_in[14];
    const float* n2w1 = (const float*)d_in[15];
    const float* n2b1 = (const float*)d_in[16];
    const float* n2w2 = (const float*)d_in[17];
    const float* n2b2 = (const float*)d_in[18];
    float* out = (float*)d_out;

    float* fws   = (float*)d_ws;
    float* UX1   = fws;                   // 10000*256
    float* UX2   = fws + 2560000;         // 10000*256
    float* proj  = fws + 5120000;         // 10000*2
    float* maskv = fws + 5140000;         // 10000
    float* eas   = fws + 5150016;         // 150000
    float* M1    = fws + 5300016;         // 128*128
    float* M2    = fws + 5316400;         // 128*128
    float* WH    = fws + 5332784;         // 128*256
    float* v1    = fws + 5365552;         // 128
    float* v2    = fws + 5365680;         // 128
    float* bu2   = fws + 5365808;         // 128
    float* bx2   = fws + 5365936;         // 128
    int*   cnt   = (int*)(fws + 5366064);
    int*   fillc = cnt + N_NODES;
    int*   eoff  = fillc + N_NODES;

    // L1-2: zero cnt, parallel histogram
    hipMemsetAsync(cnt, 0, N_NODES * sizeof(int), stream);
    count_kernel<<<EBLOCKS, 256, 0, stream>>>(idxs, cnt, E_EDGES);

    // L3: prefix-scan (block 0, zeroes fillc) + all weight folds
    scanfold_kernel<<<41, 256, 0, stream>>>(mw2, mb2, nw1, nb2, nw2,
                                            m2w1, m2b1, m2w2, m2b2, n2w1, n2b1,
                                            M1, M2, WH, v1, v2, bu2, bx2,
                                            cnt, eoff, maskv, fillc);

    // L4: CSR fill (587 blocks) + UX1 GEMM (628 blocks)
    fillgemm_kernel<<<EBLOCKS + GEMM_BLOCKS, 256, 0, stream>>>(
        idxs, eatt, eoff, fillc, eas,
        x, mw1, nw1, mb1, nb1, v1, maskv, UX1, N_NODES);

    // L5: both layers' node pipeline tail in one kernel
    fused_tail_kernel<<<313, 256, 0, stream>>>(UX1, mw1 + 784 * 128, eas, eoff, cnt,
                                               M1, WH, bu2, bx2, v2,
                                               m2w1 + 128 * 128, M2,
                                               n2w2, n2b2,
                                               UX2, proj, N_NODES);

    // L6: per-edge squared distances
    dist_kernel<<<EBLOCKS, 256, 0, stream>>>(proj, idxs, out, E_EDGES);
}

// Round 11
// 302.242 us; speedup vs baseline: 1.4997x; 1.1879x over previous
//
#include <hip/hip_runtime.h>

#define N_NODES 10000
#define E_EDGES 150000
#define KNB     15
#define EBLOCKS 587   // ceil(E/256)
#define GEMM_BLOCKS 628   // 157 rowBlks x 4 colBlks

// ---------------------------------------------------------------------------
// CSR count: parallel global atomics — NEVER single-block this (R7 lesson).
// ---------------------------------------------------------------------------
__global__ void count_kernel(const int* __restrict__ idxs, int* __restrict__ cnt, int e) {
    int i = blockIdx.x * blockDim.x + threadIdx.x;
    if (i < e) atomicAdd(&cnt[idxs[i]], 1);
}

// ---------------------------------------------------------------------------
// gemm_tile2 (MR=2) — weight-space folds only
// ---------------------------------------------------------------------------
__device__ __forceinline__
void gemm_tile2(const float* __restrict__ A, int K,
                const float* __restrict__ Blo, const float* __restrict__ Bhi, int ldB,
                float* __restrict__ C, int ldC, int M,
                int rowBlk, int colBlk) {
    __shared__ float As2[16][34];
    __shared__ float Bs2[16][64];
    int tid = threadIdx.x;
    int tn  = tid & 15, tm = tid >> 4;
    int arow = tid >> 3, acB = (tid & 7) << 1;
    int brow = tid >> 4, bcol = (tid & 15) << 2;
    int rowBase = rowBlk * 32, colBase = colBlk * 64;

    bool half = (Bhi != nullptr) && (colBase >= 128);
    const float* B = half ? Bhi : Blo;
    int bj = colBase - (half ? 128 : 0) + bcol;

    float2 av; float4 bv;
    auto loadA = [&](int k0, float2& dst) {
        int gr = rowBase + arow;
        if (gr < M) dst = *(const float2*)(A + (size_t)gr * K + k0 + acB);
        else { dst.x = dst.y = 0.f; }
    };
    auto loadB = [&](int k0, float4& dst) {
        dst = *(const float4*)(B + (size_t)(k0 + brow) * ldB + bj);
    };
    loadA(0, av); loadB(0, bv);

    float acc[2][4] = {};
    for (int k0 = 0; k0 < K; k0 += 16) {
        __syncthreads();
        As2[acB + 0][arow] = av.x; As2[acB + 1][arow] = av.y;
        *(float4*)&Bs2[brow][bcol] = bv;
        __syncthreads();
        if (k0 + 16 < K) { loadA(k0 + 16, av); loadB(k0 + 16, bv); }
#pragma unroll
        for (int k = 0; k < 16; ++k) {
            float4 b = *(const float4*)&Bs2[k][tn << 2];
            float2 a = *(const float2*)&As2[k][tm << 1];
            acc[0][0] = fmaf(a.x, b.x, acc[0][0]); acc[0][1] = fmaf(a.x, b.y, acc[0][1]);
            acc[0][2] = fmaf(a.x, b.z, acc[0][2]); acc[0][3] = fmaf(a.x, b.w, acc[0][3]);
            acc[1][0] = fmaf(a.y, b.x, acc[1][0]); acc[1][1] = fmaf(a.y, b.y, acc[1][1]);
            acc[1][2] = fmaf(a.y, b.z, acc[1][2]); acc[1][3] = fmaf(a.y, b.w, acc[1][3]);
        }
    }
#pragma unroll
    for (int i = 0; i < 2; ++i) {
        int row = rowBase + tm * 2 + i;
        if (row >= M) continue;
#pragma unroll
        for (int j = 0; j < 4; ++j)
            C[(size_t)row * ldC + colBase + (tn << 2) + j] = acc[i][j];
    }
}

// ---------------------------------------------------------------------------
// scanfold: block 0 = prefix-scan of cnt (writes eoff/maskv, zeroes fillc);
// blocks 1..40 = weight folds (M1, M2, WH, v1, v2, bu2, bx2).
// ---------------------------------------------------------------------------
__global__ __launch_bounds__(256)
void scanfold_kernel(const float* __restrict__ mw2, const float* __restrict__ mb2,
                     const float* __restrict__ nw1, const float* __restrict__ nb2,
                     const float* __restrict__ nw2,
                     const float* __restrict__ m2w1, const float* __restrict__ m2b1,
                     const float* __restrict__ m2w2, const float* __restrict__ m2b2,
                     const float* __restrict__ n2w1, const float* __restrict__ n2b1,
                     float* __restrict__ M1, float* __restrict__ M2,
                     float* __restrict__ WH,
                     float* __restrict__ v1, float* __restrict__ v2,
                     float* __restrict__ bu2, float* __restrict__ bx2,
                     const int* __restrict__ cnt, int* __restrict__ eoff,
                     float* __restrict__ maskv, int* __restrict__ fillc) {
    int b = blockIdx.x;
    if (b == 0) {
        __shared__ int ssum[256];
        int tid = threadIdx.x;
        const int CH = 40;
        int base = tid * CH;
        int v[CH]; int s = 0;
#pragma unroll
        for (int q = 0; q < CH; ++q) {
            int i = base + q;
            v[q] = (i < N_NODES) ? cnt[i] : 0;
            s += v[q];
        }
        ssum[tid] = s;
        __syncthreads();
        for (int off = 1; off < 256; off <<= 1) {
            int t = (tid >= off) ? ssum[tid - off] : 0;
            __syncthreads();
            ssum[tid] += t;
            __syncthreads();
        }
        int ex = ssum[tid] - s;
#pragma unroll
        for (int q = 0; q < CH; ++q) {
            int i = base + q;
            if (i < N_NODES) {
                eoff[i]  = ex;
                maskv[i] = (v[q] > 0) ? 1.f : 0.f;
                fillc[i] = 0;
                ex += v[q];
            }
        }
        return;
    }
    b -= 1;
    if (b < 8) {
        gemm_tile2(mw2, 784, nw1 + 784 * 128, nullptr, 128, M1, 128, 128, b >> 1, b & 1);
    } else if (b < 16) {
        int t = b - 8;
        gemm_tile2(m2w2, 128, n2w1 + 128 * 128, nullptr, 128, M2, 128, 128, t >> 1, t & 1);
    } else if (b < 32) {
        int t = b - 16;
        gemm_tile2(nw2, 128, m2w1, n2w1, 128, WH, 256, 128, t >> 2, t & 3);
    } else {
        __shared__ float red[256];
        int t  = (b - 32) >> 1;
        int j  = ((b - 32) & 1) * 64 + (threadIdx.x & 63);
        int kq = threadIdx.x >> 6;
        const float* bvec; const float* Bv; const float* add; float* out; int Kv;
        if (t == 0)      { bvec = mb2;  Bv = nw1 + 784 * 128;  add = nullptr; out = v1;  Kv = 784; }
        else if (t == 1) { bvec = m2b2; Bv = n2w1 + 128 * 128; add = nullptr; out = v2;  Kv = 128; }
        else if (t == 2) { bvec = nb2;  Bv = m2w1;             add = m2b1;    out = bu2; Kv = 128; }
        else             { bvec = nb2;  Bv = n2w1;             add = n2b1;    out = bx2; Kv = 128; }
        float acc = 0.f;
        for (int k = kq; k < Kv; k += 4) acc = fmaf(bvec[k], Bv[k * 128 + j], acc);
        red[threadIdx.x] = acc;
        __syncthreads();
        if (threadIdx.x < 64) {
            float tot = red[threadIdx.x] + red[threadIdx.x + 64] +
                        red[threadIdx.x + 128] + red[threadIdx.x + 192];
            out[j] = tot + (add ? add[j] : 0.f);
        }
    }
}

// ---------------------------------------------------------------------------
// gemm784 tile — R3/R8-proven: 256 thr, 64x64 tile, 4x4 micro,
// LDS A(transposed, pad 68) + B, register prefetch, 2 barriers/k-tile.
// ---------------------------------------------------------------------------
__device__ __forceinline__
void gemm784_tile(const float* __restrict__ A,
                  const float* __restrict__ B0, const float* __restrict__ B1,
                  const float* __restrict__ biasLo, const float* __restrict__ biasHi,
                  const float* __restrict__ vhi, const float* __restrict__ rowmask,
                  float* __restrict__ C, int M, int gb) {
    __shared__ float As[16][68];
    __shared__ float Bs[16][64];
    int rb = gb >> 2, cb = gb & 3;
    int tid = threadIdx.x;
    int tm = tid >> 4, tn = tid & 15;
    int arow = tid >> 2, ac4 = (tid & 3) << 2;
    int brow = tid >> 4, bc4 = (tid & 15) << 2;
    int rowBase = rb * 64, colBase = cb * 64;
    bool hi = colBase >= 128;
    const float* B    = hi ? B1 : B0;
    const float* bias = hi ? biasHi : biasLo;
    int bj = ((cb & 1) << 6) + bc4;

    int gr = rowBase + arow; if (gr > M - 1) gr = M - 1;   // clamp; stores guarded
    const float* Ap = A + (size_t)gr * 784;

    float4 av, bv;
    av = *(const float4*)(Ap + ac4);
    bv = *(const float4*)(B + (size_t)brow * 128 + bj);

    float acc[4][4] = {};
    for (int k0 = 0; k0 < 784; k0 += 16) {
        __syncthreads();
        As[ac4 + 0][arow] = av.x;
        As[ac4 + 1][arow] = av.y;
        As[ac4 + 2][arow] = av.z;
        As[ac4 + 3][arow] = av.w;
        *(float4*)&Bs[brow][bc4] = bv;
        __syncthreads();
        if (k0 + 16 < 784) {
            av = *(const float4*)(Ap + k0 + 16 + ac4);
            bv = *(const float4*)(B + (size_t)(k0 + 16 + brow) * 128 + bj);
        }
#pragma unroll
        for (int k = 0; k < 16; ++k) {
            float4 a = *(const float4*)&As[k][tm << 2];
            float4 b = *(const float4*)&Bs[k][tn << 2];
            acc[0][0] = fmaf(a.x, b.x, acc[0][0]); acc[0][1] = fmaf(a.x, b.y, acc[0][1]);
            acc[0][2] = fmaf(a.x, b.z, acc[0][2]); acc[0][3] = fmaf(a.x, b.w, acc[0][3]);
            acc[1][0] = fmaf(a.y, b.x, acc[1][0]); acc[1][1] = fmaf(a.y, b.y, acc[1][1]);
            acc[1][2] = fmaf(a.y, b.z, acc[1][2]); acc[1][3] = fmaf(a.y, b.w, acc[1][3]);
            acc[2][0] = fmaf(a.z, b.x, acc[2][0]); acc[2][1] = fmaf(a.z, b.y, acc[2][1]);
            acc[2][2] = fmaf(a.z, b.z, acc[2][2]); acc[2][3] = fmaf(a.z, b.w, acc[2][3]);
            acc[3][0] = fmaf(a.w, b.x, acc[3][0]); acc[3][1] = fmaf(a.w, b.y, acc[3][1]);
            acc[3][2] = fmaf(a.w, b.z, acc[3][2]); acc[3][3] = fmaf(a.w, b.w, acc[3][3]);
        }
    }

#pragma unroll
    for (int i = 0; i < 4; ++i) {
        int row = rowBase + (tm << 2) + i;
        if (row >= M) continue;
        float rm = hi ? rowmask[row] : 0.f;
#pragma unroll
        for (int j = 0; j < 4; ++j) {
            int gcol = colBase + (tn << 2) + j;
            int cj   = gcol & 127;
            float v = acc[i][j] + bias[cj];
            if (hi) v = fmaf(rm, vhi[cj], v);
            C[(size_t)row * 256 + gcol] = v;
        }
    }
}

// ---------------------------------------------------------------------------
// fillgemm: blocks [0,587) CSR fill; blocks [587,1215) gemm784.
// ---------------------------------------------------------------------------
__global__ __launch_bounds__(256)
void fillgemm_kernel(const int* __restrict__ idxs, const float* __restrict__ ea,
                     const int* __restrict__ eoff, int* __restrict__ fillc,
                     float* __restrict__ eas,
                     const float* __restrict__ A,
                     const float* __restrict__ B0, const float* __restrict__ B1,
                     const float* __restrict__ biasLo, const float* __restrict__ biasHi,
                     const float* __restrict__ vhi, const float* __restrict__ rowmask,
                     float* __restrict__ C, int M) {
    int gb = blockIdx.x;
    if (gb < EBLOCKS) {
        int i = gb * 256 + threadIdx.x;
        if (i < E_EDGES) {
            int s = idxs[i];
            int p = atomicAdd(&fillc[s], 1);
            eas[eoff[s] + p] = ea[i];
        }
        return;
    }
    gemm784_tile(A, B0, B1, biasLo, biasHi, vhi, rowmask, C, M, gb - EBLOCKS);
}

// ---------------------------------------------------------------------------
// tail16: R9-verified tail phases at 16 rows/block, grid 625 (2.4 blocks/CU,
// LDS ~39KB -> 4 blocks/CU capacity; tail is grid/latency-bound so block
// count is the lever — R10's 313-block merge was the mistake).
//   msg1:   mhT = mean_e relu(u1 + ea*w1last)
//   phase1: ts  = relu(xn1 + mhT@M1)
//   phase2: UX2 = [ts@WHu+bu2 | ts@WHx+bx2+maskv*v2]
//   msg2:   mhT = mean_e relu(u2 + ea*w2last)
//   phase4: z2  = relu(xn2 + mhT@M2); proj = z2@pw + pb
// ---------------------------------------------------------------------------
__global__ __launch_bounds__(256)
void tail16_kernel(const float* __restrict__ UX1, const float* __restrict__ w1last,
                   const float* __restrict__ eas, const int* __restrict__ eoff,
                   const int* __restrict__ cnt, const float* __restrict__ maskv,
                   const float* __restrict__ M1, const float* __restrict__ WH,
                   const float* __restrict__ bu2, const float* __restrict__ bx2,
                   const float* __restrict__ v2,
                   const float* __restrict__ w2last, const float* __restrict__ M2,
                   const float* __restrict__ pw, const float* __restrict__ pb,
                   float* __restrict__ UX2, float* __restrict__ proj) {
    __shared__ float Bs[16][264];    // B staging (all GEMM phases)
    __shared__ float mhT[128][18];   // msg means [k][m]
    __shared__ float ts[16][132];    // z1 rows
    __shared__ float ebuf[1024];     // CSR edge window
    int rowBase = blockIdx.x * 16;   // 625*16 = 10000 exact
    int tid = threadIdx.x;
    int tm2 = tid >> 5;              // 0..7 -> rows 2*tm2, 2*tm2+1
    int tn  = tid & 31;

    auto msg_phase = [&](const float* __restrict__ U, const float* __restrict__ wl) {
        int d = tid & 127, sub = tid >> 7;
        float w = wl[d];
        float uu[8], sum[8];
        int es[8], ec[8];
#pragma unroll
        for (int it = 0; it < 8; ++it) {
            int n  = rowBase + it * 2 + sub;
            ec[it] = cnt[n];
            es[it] = eoff[n];
            uu[it] = U[(size_t)n * 256 + d];
            sum[it] = 0.f;
        }
        int ebase = eoff[rowBase];
        int eend  = (rowBase + 16 < N_NODES) ? eoff[rowBase + 16] : E_EDGES;
        for (int w0 = ebase; w0 < eend; w0 += 1024) {
            int wlen = min(1024, eend - w0);
            __syncthreads();
            for (int q = tid; q < wlen; q += 256) ebuf[q] = eas[w0 + q];
            __syncthreads();
#pragma unroll
            for (int it = 0; it < 8; ++it) {
                int lo = max(es[it], w0), hiE = min(es[it] + ec[it], w0 + wlen);
                for (int e = lo; e < hiE; ++e)
                    sum[it] += fmaxf(fmaf(ebuf[e - w0], w, uu[it]), 0.f);
            }
        }
#pragma unroll
        for (int it = 0; it < 8; ++it)
            mhT[d][it * 2 + sub] = (ec[it] > 0) ? sum[it] / (float)ec[it] : 0.f;
    };

    // ===== msg1 =====
    msg_phase(UX1, w1last);
    __syncthreads();

    // ===== phase1: ts = relu(xn1 + mhT @ M1), 16x128 =====
    {
        float acc[2][4] = {};
        for (int k0 = 0; k0 < 128; k0 += 16) {
            int kr = tid >> 4, c8 = (tid & 15) << 3;
            *(float4*)&Bs[kr][c8]     = *(const float4*)(M1 + (size_t)(k0 + kr) * 128 + c8);
            *(float4*)&Bs[kr][c8 + 4] = *(const float4*)(M1 + (size_t)(k0 + kr) * 128 + c8 + 4);
            __syncthreads();
#pragma unroll
            for (int k = 0; k < 16; ++k) {
                float2 a = *(const float2*)&mhT[k0 + k][tm2 << 1];
                float4 b = *(const float4*)&Bs[k][tn << 2];
                acc[0][0] = fmaf(a.x, b.x, acc[0][0]); acc[0][1] = fmaf(a.x, b.y, acc[0][1]);
                acc[0][2] = fmaf(a.x, b.z, acc[0][2]); acc[0][3] = fmaf(a.x, b.w, acc[0][3]);
                acc[1][0] = fmaf(a.y, b.x, acc[1][0]); acc[1][1] = fmaf(a.y, b.y, acc[1][1]);
                acc[1][2] = fmaf(a.y, b.z, acc[1][2]); acc[1][3] = fmaf(a.y, b.w, acc[1][3]);
            }
            __syncthreads();
        }
#pragma unroll
        for (int i = 0; i < 2; ++i) {
            int row = rowBase + (tm2 << 1) + i;
            float4 xn = *(const float4*)(UX1 + (size_t)row * 256 + 128 + (tn << 2));
            float4 o;
            o.x = fmaxf(acc[i][0] + xn.x, 0.f);
            o.y = fmaxf(acc[i][1] + xn.y, 0.f);
            o.z = fmaxf(acc[i][2] + xn.z, 0.f);
            o.w = fmaxf(acc[i][3] + xn.w, 0.f);
            *(float4*)&ts[(tm2 << 1) + i][tn << 2] = o;
        }
    }

    // ===== phase2: UX2 = ts @ WH + bias (+maskv*v2 on hi), 16x256 =====
    {
        float acc[2][8] = {};
        for (int k0 = 0; k0 < 128; k0 += 16) {
            int kr = tid >> 4, c4 = (tid & 15) << 2;
#pragma unroll
            for (int p = 0; p < 4; ++p)
                *(float4*)&Bs[kr][c4 + p * 64] =
                    *(const float4*)(WH + (size_t)(k0 + kr) * 256 + c4 + p * 64);
            __syncthreads();   // also orders ts writes before reads
#pragma unroll
            for (int k = 0; k < 16; ++k) {
                float4 b0 = *(const float4*)&Bs[k][tn << 3];
                float4 b1 = *(const float4*)&Bs[k][(tn << 3) + 4];
                float br[8] = {b0.x, b0.y, b0.z, b0.w, b1.x, b1.y, b1.z, b1.w};
#pragma unroll
                for (int i = 0; i < 2; ++i) {
                    float a = ts[(tm2 << 1) + i][k0 + k];
#pragma unroll
                    for (int j = 0; j < 8; ++j)
                        acc[i][j] = fmaf(a, br[j], acc[i][j]);
                }
            }
            __syncthreads();
        }
        bool hi = tn >= 16;
        const float* bias = hi ? bx2 : bu2;
#pragma unroll
        for (int i = 0; i < 2; ++i) {
            int row = rowBase + (tm2 << 1) + i;
            float rm = maskv[row];
            float4 o0, o1; float* po0 = (float*)&o0; float* po1 = (float*)&o1;
#pragma unroll
            for (int j = 0; j < 4; ++j) {
                int cj0 = ((tn << 3) + j) & 127, cj1 = ((tn << 3) + 4 + j) & 127;
                float q0 = acc[i][j]     + bias[cj0];
                float q1 = acc[i][4 + j] + bias[cj1];
                if (hi) { q0 = fmaf(rm, v2[cj0], q0); q1 = fmaf(rm, v2[cj1], q1); }
                po0[j] = q0; po1[j] = q1;
            }
            float* orow = UX2 + (size_t)row * 256 + (tn << 3);
            *(float4*)orow       = o0;
            *(float4*)(orow + 4) = o1;
        }
    }
    __syncthreads();   // UX2 block-visible (own rows only are read below)

    // ===== msg2 =====
    msg_phase(UX2, w2last);

    // ===== phase4: z2 = relu(xn2 + mhT@M2); proj = z2@pw + pb =====
    {
        float acc[2][4] = {};
        for (int k0 = 0; k0 < 128; k0 += 16) {
            int kr = tid >> 4, c8 = (tid & 15) << 3;
            *(float4*)&Bs[kr][c8]     = *(const float4*)(M2 + (size_t)(k0 + kr) * 128 + c8);
            *(float4*)&Bs[kr][c8 + 4] = *(const float4*)(M2 + (size_t)(k0 + kr) * 128 + c8 + 4);
            __syncthreads();   // also orders msg2's mhT writes
#pragma unroll
            for (int k = 0; k < 16; ++k) {
                float2 a = *(const float2*)&mhT[k0 + k][tm2 << 1];
                float4 b = *(const float4*)&Bs[k][tn << 2];
                acc[0][0] = fmaf(a.x, b.x, acc[0][0]); acc[0][1] = fmaf(a.x, b.y, acc[0][1]);
                acc[0][2] = fmaf(a.x, b.z, acc[0][2]); acc[0][3] = fmaf(a.x, b.w, acc[0][3]);
                acc[1][0] = fmaf(a.y, b.x, acc[1][0]); acc[1][1] = fmaf(a.y, b.y, acc[1][1]);
                acc[1][2] = fmaf(a.y, b.z, acc[1][2]); acc[1][3] = fmaf(a.y, b.w, acc[1][3]);
            }
            __syncthreads();
        }
        float pp0[2], pp1[2];
#pragma unroll
        for (int i = 0; i < 2; ++i) {
            int row = rowBase + (tm2 << 1) + i;
            float4 xn = *(const float4*)(UX2 + (size_t)row * 256 + 128 + (tn << 2));
            float t0 = fmaxf(acc[i][0] + xn.x, 0.f);
            float t1 = fmaxf(acc[i][1] + xn.y, 0.f);
            float t2 = fmaxf(acc[i][2] + xn.z, 0.f);
            float t3 = fmaxf(acc[i][3] + xn.w, 0.f);
            int c = tn << 2;
            pp0[i] = fmaf(t3, pw[2*(c+3)],   fmaf(t2, pw[2*(c+2)],   fmaf(t1, pw[2*(c+1)],   t0 * pw[2*c])));
            pp1[i] = fmaf(t3, pw[2*(c+3)+1], fmaf(t2, pw[2*(c+2)+1], fmaf(t1, pw[2*(c+1)+1], t0 * pw[2*c+1])));
        }
        for (int off = 16; off > 0; off >>= 1) {
            pp0[0] += __shfl_xor(pp0[0], off, 64);
            pp0[1] += __shfl_xor(pp0[1], off, 64);
            pp1[0] += __shfl_xor(pp1[0], off, 64);
            pp1[1] += __shfl_xor(pp1[1], off, 64);
        }
        if (tn == 0) {
#pragma unroll
            for (int i = 0; i < 2; ++i) {
                int row = rowBase + (tm2 << 1) + i;
                proj[2 * row]     = pp0[i] + pb[0];
                proj[2 * row + 1] = pp1[i] + pb[1];
            }
        }
    }
}

__global__ void dist_kernel(const float* __restrict__ proj, const int* __restrict__ idxs,
                            float* __restrict__ out, int e) {
    int i = blockIdx.x * blockDim.x + threadIdx.x;
    if (i >= e) return;
    int n = i / KNB;
    int m = idxs[i];
    float2 pn = *(const float2*)(proj + 2 * n);
    float2 pm = *(const float2*)(proj + 2 * m);
    float dx = pn.x - pm.x;
    float dy = pn.y - pm.y;
    out[i] = dx * dx + dy * dy;
}

// ---------------------------------------------------------------------------
extern "C" void kernel_launch(void* const* d_in, const int* in_sizes, int n_in,
                              void* d_out, int out_size, void* d_ws, size_t ws_size,
                              hipStream_t stream) {
    (void)in_sizes; (void)n_in; (void)out_size; (void)ws_size;
    const float* x    = (const float*)d_in[0];
    const float* eatt = (const float*)d_in[1];
    const int*   idxs = (const int*)d_in[2];
    const float* mw1  = (const float*)d_in[3];
    const float* mb1  = (const float*)d_in[4];
    const float* mw2  = (const float*)d_in[5];
    const float* mb2  = (const float*)d_in[6];
    const float* nw1  = (const float*)d_in[7];
    const float* nb1  = (const float*)d_in[8];
    const float* nw2  = (const float*)d_in[9];
    const float* nb2  = (const float*)d_in[10];
    const float* m2w1 = (const float*)d_in[11];
    const float* m2b1 = (const float*)d_in[12];
    const float* m2w2 = (const float*)d_in[13];
    const float* m2b2 = (const float*)d_in[14];
    const float* n2w1 = (const float*)d_in[15];
    const float* n2b1 = (const float*)d_in[16];
    const float* n2w2 = (const float*)d_in[17];
    const float* n2b2 = (const float*)d_in[18];
    float* out = (float*)d_out;

    float* fws   = (float*)d_ws;
    float* UX1   = fws;                   // 10000*256
    float* UX2   = fws + 2560000;         // 10000*256
    float* proj  = fws + 5120000;         // 10000*2
    float* maskv = fws + 5140000;         // 10000
    float* eas   = fws + 5150016;         // 150000
    float* M1    = fws + 5300016;         // 128*128
    float* M2    = fws + 5316400;         // 128*128
    float* WH    = fws + 5332784;         // 128*256
    float* v1    = fws + 5365552;         // 128
    float* v2    = fws + 5365680;         // 128
    float* bu2   = fws + 5365808;         // 128
    float* bx2   = fws + 5365936;         // 128
    int*   cnt   = (int*)(fws + 5366064);
    int*   fillc = cnt + N_NODES;
    int*   eoff  = fillc + N_NODES;

    // L1-2: zero cnt, parallel histogram
    hipMemsetAsync(cnt, 0, N_NODES * sizeof(int), stream);
    count_kernel<<<EBLOCKS, 256, 0, stream>>>(idxs, cnt, E_EDGES);

    // L3: prefix-scan (block 0, zeroes fillc) + all weight folds
    scanfold_kernel<<<41, 256, 0, stream>>>(mw2, mb2, nw1, nb2, nw2,
                                            m2w1, m2b1, m2w2, m2b2, n2w1, n2b1,
                                            M1, M2, WH, v1, v2, bu2, bx2,
                                            cnt, eoff, maskv, fillc);

    // L4: CSR fill (587 blocks) + UX1 GEMM (628 blocks)
    fillgemm_kernel<<<EBLOCKS + GEMM_BLOCKS, 256, 0, stream>>>(
        idxs, eatt, eoff, fillc, eas,
        x, mw1, nw1, mb1, nb1, v1, maskv, UX1, N_NODES);

    // L5: tail at 16 rows/block, 625 blocks (grid-parallelism is the lever)
    tail16_kernel<<<625, 256, 0, stream>>>(UX1, mw1 + 784 * 128, eas, eoff, cnt, maskv,
                                           M1, WH, bu2, bx2, v2,
                                           m2w1 + 128 * 128, M2,
                                           n2w2, n2b2,
                                           UX2, proj);

    // L6: per-edge squared distances
    dist_kernel<<<EBLOCKS, 256, 0, stream>>>(proj, idxs, out, E_EDGES);
}